// Round 1
// baseline (2501.541 us; speedup 1.0000x reference)
//
#include <hip/hip_runtime.h>
#include <math.h>

#define NUM_USERS 100000
#define NUM_ITEMS 50000
#define NN 150000
#define DD 64
#define EE 1250000
#define SS 400000
#define TAU 0.2f
#define EDGE_BIAS 0.5f

// ---------------------------------------------------------------------------
// init: x_cur = y_cur = out_x = out_y = ego; zero x_next/y_next; winner = -1
// ---------------------------------------------------------------------------
__global__ void init_kernel(const float* __restrict__ user, const float* __restrict__ item,
                            float* __restrict__ x_cur, float* __restrict__ y_cur,
                            float* __restrict__ x_next, float* __restrict__ y_next,
                            float* __restrict__ outx, float* __restrict__ outy,
                            int* __restrict__ winner, double* __restrict__ gate_sum) {
    int i = blockIdx.x * blockDim.x + threadIdx.x;
    if (i < NN * DD) {
        float v = (i < NUM_USERS * DD) ? user[i] : item[i - NUM_USERS * DD];
        x_cur[i] = v; y_cur[i] = v;
        outx[i] = v;  outy[i] = v;
        x_next[i] = 0.f; y_next[i] = 0.f;
    }
    if (i < EE) winner[i] = -1;
    if (i == 0) *gate_sum = 0.0;
}

// ---------------------------------------------------------------------------
// gate MLP: one wave per sample s. lane holds cat[lane] (=ego[su]) and
// cat[64+lane] (=ego[sv]); W1 column for j=lane hoisted into 128 VGPRs.
// ---------------------------------------------------------------------------
__global__ __launch_bounds__(256) void gate_kernel(
        const float* __restrict__ user, const float* __restrict__ item,
        const int* __restrict__ rows, const int* __restrict__ cols,
        const int* __restrict__ sidx, const float* __restrict__ eps,
        const float* __restrict__ W1, const float* __restrict__ b1,
        const float* __restrict__ W2, const float* __restrict__ b2,
        float* __restrict__ gate, double* __restrict__ gate_sum) {
    const int lane = threadIdx.x & 63;
    const int wib = threadIdx.x >> 6;            // wave in block (4 waves / 256 thr)
    const int gwave = blockIdx.x * 4 + wib;
    const int nwaves = gridDim.x * 4;

    // hoist weights (uniform across s)
    float w1r[128];
#pragma unroll
    for (int k = 0; k < 128; ++k) w1r[k] = W1[k * DD + lane];
    const float b1v = b1[lane];
    const float w2v = W2[lane];
    const float b2v = b2[0];

    double partial = 0.0;

    for (int s = gwave; s < SS; s += nwaves) {
        const int e  = sidx[s];
        const int su = rows[e];
        const int sv = cols[e];
        const float a = (su < NUM_USERS) ? user[su * DD + lane]
                                         : item[(su - NUM_USERS) * DD + lane];
        const float b = (sv < NUM_USERS) ? user[sv * DD + lane]
                                         : item[(sv - NUM_USERS) * DD + lane];
        float h = b1v;
#pragma unroll
        for (int k = 0; k < 64; ++k) h = fmaf(__shfl(a, k), w1r[k], h);
#pragma unroll
        for (int k = 0; k < 64; ++k) h = fmaf(__shfl(b, k), w1r[64 + k], h);
        h = fmaxf(h, 0.f) * w2v;
        // butterfly reduce across 64 lanes
#pragma unroll
        for (int off = 32; off >= 1; off >>= 1) h += __shfl_xor(h, off);
        const float logit = h + b2v;

        const float ev  = eps[s] * (1.f - 2e-6f) + 1e-6f;
        const float gum = logf(ev) - log1pf(-ev);
        const float z   = (logit + gum) * (1.f / TAU);
        const float g   = 1.f / (1.f + expf(-z)) + EDGE_BIAS;
        if (lane == 0) { gate[s] = g; partial += (double)g; }
    }

    __shared__ double sd[4];
    if (lane == 0) sd[wib] = partial;
    __syncthreads();
    if (threadIdx.x == 0) {
        double t = sd[0] + sd[1] + sd[2] + sd[3];
        atomicAdd(gate_sum, t);
    }
}

// ---------------------------------------------------------------------------
// numpy last-write-wins scatter: winner[e] = max s with sidx[s]==e
// ---------------------------------------------------------------------------
__global__ void winner_kernel(const int* __restrict__ sidx, int* __restrict__ winner) {
    int s = blockIdx.x * blockDim.x + threadIdx.x;
    if (s < SS) atomicMax(&winner[sidx[s]], s);
}

__global__ void mvals_kernel(const float* __restrict__ vals, const int* __restrict__ winner,
                             const float* __restrict__ gate, float* __restrict__ mvals) {
    int e = blockIdx.x * blockDim.x + threadIdx.x;
    if (e < EE) {
        int w = winner[e];
        float v = vals[e];
        mvals[e] = (w >= 0) ? v * gate[w] : v;
    }
}

// ---------------------------------------------------------------------------
// fused dual-chain SpMM: one wave per edge, lane = dim, atomic scatter-add
// ---------------------------------------------------------------------------
__global__ void spmm_kernel(const int* __restrict__ rows, const int* __restrict__ cols,
                            const float* __restrict__ vals, const float* __restrict__ mvals,
                            const float* __restrict__ x_cur, const float* __restrict__ y_cur,
                            float* __restrict__ x_next, float* __restrict__ y_next) {
    int t = blockIdx.x * blockDim.x + threadIdx.x;
    int e = t >> 6;
    int lane = t & 63;
    if (e < EE) {
        int r = rows[e], c = cols[e];
        float v = vals[e], mv = mvals[e];
        float xv = x_cur[c * DD + lane];
        float yv = y_cur[c * DD + lane];
        atomicAdd(&x_next[r * DD + lane], v * xv);
        atomicAdd(&y_next[r * DD + lane], mv * yv);
    }
}

// ---------------------------------------------------------------------------
// fold layer result into running sum; rotate cur<-next, re-zero next.
// final fold applies the 1/(L+1) = 0.25 mean scale.
// ---------------------------------------------------------------------------
__global__ void fold_kernel(float* __restrict__ x_next, float* __restrict__ y_next,
                            float* __restrict__ x_cur, float* __restrict__ y_cur,
                            float* __restrict__ outx, float* __restrict__ outy,
                            int final_pass) {
    int i = blockIdx.x * blockDim.x + threadIdx.x;
    if (i < NN * DD) {
        float xv = x_next[i], yv = y_next[i];
        if (final_pass) {
            outx[i] = (outx[i] + xv) * 0.25f;
            outy[i] = (outy[i] + yv) * 0.25f;
        } else {
            outx[i] += xv; outy[i] += yv;
            x_cur[i] = xv; y_cur[i] = yv;
            x_next[i] = 0.f; y_next[i] = 0.f;
        }
    }
}

__global__ void final_kernel(const double* __restrict__ gate_sum, float* __restrict__ out_scalar) {
    if (threadIdx.x == 0) out_scalar[0] = (float)(*gate_sum * (1.0 / (double)SS));
}

extern "C" void kernel_launch(void* const* d_in, const int* in_sizes, int n_in,
                              void* d_out, int out_size, void* d_ws, size_t ws_size,
                              hipStream_t stream) {
    const float* user = (const float*)d_in[0];
    const float* item = (const float*)d_in[1];
    const int*   rows = (const int*)d_in[2];
    const int*   cols = (const int*)d_in[3];
    const float* vals = (const float*)d_in[4];
    const int*   sidx = (const int*)d_in[5];
    const float* eps  = (const float*)d_in[6];
    const float* W1   = (const float*)d_in[7];
    const float* b1   = (const float*)d_in[8];
    const float* W2   = (const float*)d_in[9];
    const float* b2   = (const float*)d_in[10];

    float* out  = (float*)d_out;
    const size_t ND = (size_t)NN * DD;           // 9,600,000
    float* outx = out;
    float* outy = out + ND;
    float* out_scalar = out + 2 * ND;

    float* ws = (float*)d_ws;
    float* x_cur  = ws;
    float* y_cur  = ws + ND;
    float* x_next = ws + 2 * ND;
    float* y_next = ws + 3 * ND;
    float* gate   = ws + 4 * ND;
    float* mvals  = gate + SS;
    int*   winner = (int*)(mvals + EE);
    double* gate_sum = (double*)(winner + EE);   // byte offset 165,200,000 (8B aligned)

    const int B = 256;
    const int grid_ND   = (int)((ND + B - 1) / B);          // 37500
    const int grid_S    = (SS + B - 1) / B;                 // 1563
    const int grid_E    = (EE + B - 1) / B;                 // 4883
    const int grid_spmm = (int)(((size_t)EE * 64 + B - 1) / B); // 312500

    init_kernel<<<grid_ND, B, 0, stream>>>(user, item, x_cur, y_cur, x_next, y_next,
                                           outx, outy, winner, gate_sum);
    gate_kernel<<<4096, B, 0, stream>>>(user, item, rows, cols, sidx, eps,
                                        W1, b1, W2, b2, gate, gate_sum);
    winner_kernel<<<grid_S, B, 0, stream>>>(sidx, winner);
    mvals_kernel<<<grid_E, B, 0, stream>>>(vals, winner, gate, mvals);

    for (int l = 0; l < 3; ++l) {
        spmm_kernel<<<grid_spmm, B, 0, stream>>>(rows, cols, vals, mvals,
                                                 x_cur, y_cur, x_next, y_next);
        fold_kernel<<<grid_ND, B, 0, stream>>>(x_next, y_next, x_cur, y_cur,
                                               outx, outy, (l == 2) ? 1 : 0);
    }
    final_kernel<<<1, 64, 0, stream>>>(gate_sum, out_scalar);
}

// Round 2
// 1658.346 us; speedup vs baseline: 1.5085x; 1.5085x over previous
//
#include <hip/hip_runtime.h>
#include <math.h>

#define NUM_USERS 100000
#define NUM_ITEMS 50000
#define NN 150000
#define DD 64
#define EE 1250000
#define SS 400000
#define TAU 0.2f
#define EDGE_BIAS 0.5f
#define NB_SCAN 586  // ceil(NN/256)

// ---------------------------------------------------------------------------
// init: x_cur = y_cur = out_x = out_y = ego; winner = -1; gate_sum = 0
// ---------------------------------------------------------------------------
__global__ void init_kernel(const float* __restrict__ user, const float* __restrict__ item,
                            float* __restrict__ x_cur, float* __restrict__ y_cur,
                            float* __restrict__ outx, float* __restrict__ outy,
                            int* __restrict__ winner, double* __restrict__ gate_sum) {
    int i = blockIdx.x * blockDim.x + threadIdx.x;
    if (i < NN * DD) {
        float v = (i < NUM_USERS * DD) ? user[i] : item[i - NUM_USERS * DD];
        x_cur[i] = v; y_cur[i] = v;
        outx[i] = v;  outy[i] = v;
    }
    if (i < EE) winner[i] = -1;
    if (i == 0) *gate_sum = 0.0;
}

// ---------------------------------------------------------------------------
// gate MLP: one wave per sample (unchanged this round; next target)
// ---------------------------------------------------------------------------
__global__ __launch_bounds__(256) void gate_kernel(
        const float* __restrict__ user, const float* __restrict__ item,
        const int* __restrict__ rows, const int* __restrict__ cols,
        const int* __restrict__ sidx, const float* __restrict__ eps,
        const float* __restrict__ W1, const float* __restrict__ b1,
        const float* __restrict__ W2, const float* __restrict__ b2,
        float* __restrict__ gate, double* __restrict__ gate_sum) {
    const int lane = threadIdx.x & 63;
    const int wib = threadIdx.x >> 6;
    const int gwave = blockIdx.x * 4 + wib;
    const int nwaves = gridDim.x * 4;

    float w1r[128];
#pragma unroll
    for (int k = 0; k < 128; ++k) w1r[k] = W1[k * DD + lane];
    const float b1v = b1[lane];
    const float w2v = W2[lane];
    const float b2v = b2[0];

    double partial = 0.0;

    for (int s = gwave; s < SS; s += nwaves) {
        const int e  = sidx[s];
        const int su = rows[e];
        const int sv = cols[e];
        const float a = (su < NUM_USERS) ? user[su * DD + lane]
                                         : item[(su - NUM_USERS) * DD + lane];
        const float b = (sv < NUM_USERS) ? user[sv * DD + lane]
                                         : item[(sv - NUM_USERS) * DD + lane];
        float h = b1v;
#pragma unroll
        for (int k = 0; k < 64; ++k) h = fmaf(__shfl(a, k), w1r[k], h);
#pragma unroll
        for (int k = 0; k < 64; ++k) h = fmaf(__shfl(b, k), w1r[64 + k], h);
        h = fmaxf(h, 0.f) * w2v;
#pragma unroll
        for (int off = 32; off >= 1; off >>= 1) h += __shfl_xor(h, off);
        const float logit = h + b2v;

        const float ev  = eps[s] * (1.f - 2e-6f) + 1e-6f;
        const float gum = logf(ev) - log1pf(-ev);
        const float z   = (logit + gum) * (1.f / TAU);
        const float g   = 1.f / (1.f + expf(-z)) + EDGE_BIAS;
        if (lane == 0) { gate[s] = g; partial += (double)g; }
    }

    __shared__ double sd[4];
    if (lane == 0) sd[wib] = partial;
    __syncthreads();
    if (threadIdx.x == 0) {
        double t = sd[0] + sd[1] + sd[2] + sd[3];
        atomicAdd(gate_sum, t);
    }
}

// ---------------------------------------------------------------------------
// numpy last-write-wins: winner[e] = max s with sidx[s]==e; then mvals
// ---------------------------------------------------------------------------
__global__ void winner_kernel(const int* __restrict__ sidx, int* __restrict__ winner) {
    int s = blockIdx.x * blockDim.x + threadIdx.x;
    if (s < SS) atomicMax(&winner[sidx[s]], s);
}

__global__ void mvals_kernel(const float* __restrict__ vals, const int* __restrict__ winner,
                             const float* __restrict__ gate, float* __restrict__ mvals) {
    int e = blockIdx.x * blockDim.x + threadIdx.x;
    if (e < EE) {
        int w = winner[e];
        float v = vals[e];
        mvals[e] = (w >= 0) ? v * gate[w] : v;
    }
}

// ---------------------------------------------------------------------------
// CSR build: zero deg -> histogram -> 3-kernel exclusive scan -> scatter perm
// ---------------------------------------------------------------------------
__global__ void deg_zero_kernel(int* __restrict__ deg) {
    int i = blockIdx.x * blockDim.x + threadIdx.x;
    if (i < NN) deg[i] = 0;
}

__global__ void hist_kernel(const int* __restrict__ rows, int* __restrict__ deg) {
    int e = blockIdx.x * blockDim.x + threadIdx.x;
    if (e < EE) atomicAdd(&deg[rows[e]], 1);
}

__global__ void scan1_kernel(const int* __restrict__ deg, int* __restrict__ rowptr,
                             int* __restrict__ bsum) {
    __shared__ int sh[256];
    int tid = threadIdx.x;
    int i = blockIdx.x * 256 + tid;
    int v = (i < NN) ? deg[i] : 0;
    sh[tid] = v;
    __syncthreads();
    for (int off = 1; off < 256; off <<= 1) {
        int t = (tid >= off) ? sh[tid - off] : 0;
        __syncthreads();
        sh[tid] += t;
        __syncthreads();
    }
    if (i < NN) rowptr[i] = sh[tid] - v;      // exclusive within block
    if (tid == 255) bsum[blockIdx.x] = sh[255]; // block total
}

__global__ void scan2_kernel(int* __restrict__ bsum) {
    __shared__ int sh[1024];
    int tid = threadIdx.x;
    int v = (tid < NB_SCAN) ? bsum[tid] : 0;
    sh[tid] = v;
    __syncthreads();
    for (int off = 1; off < 1024; off <<= 1) {
        int t = (tid >= off) ? sh[tid - off] : 0;
        __syncthreads();
        sh[tid] += t;
        __syncthreads();
    }
    if (tid < NB_SCAN) bsum[tid] = sh[tid] - v; // exclusive
}

__global__ void scan3_kernel(int* __restrict__ rowptr, const int* __restrict__ bsum,
                             int* __restrict__ cursor) {
    int i = blockIdx.x * blockDim.x + threadIdx.x;
    if (i < NN) {
        rowptr[i] += bsum[i >> 8];
        cursor[i] = 0;
    }
    if (i == 0) rowptr[NN] = EE;
}

__global__ void scatter_kernel(const int* __restrict__ rows, const int* __restrict__ rowptr,
                               int* __restrict__ cursor, int* __restrict__ perm) {
    int e = blockIdx.x * blockDim.x + threadIdx.x;
    if (e < EE) {
        int r = rows[e];
        int pos = rowptr[r] + atomicAdd(&cursor[r], 1);
        perm[pos] = e;
    }
}

// ---------------------------------------------------------------------------
// gather-SpMM, dual chain, fold fused. One wave per row, lane = dim.
// ---------------------------------------------------------------------------
__global__ __launch_bounds__(256) void spmm_csr_kernel(
        const int* __restrict__ rowptr, const int* __restrict__ perm,
        const int* __restrict__ cols,
        const float* __restrict__ vals, const float* __restrict__ mvals,
        const float* __restrict__ xc, const float* __restrict__ yc,
        float* __restrict__ xn, float* __restrict__ yn,
        float* __restrict__ outx, float* __restrict__ outy, int final_pass) {
    int w = (blockIdx.x * blockDim.x + threadIdx.x) >> 6;
    int lane = threadIdx.x & 63;
    if (w >= NN) return;
    int beg = rowptr[w], end = rowptr[w + 1];
    float ax = 0.f, ay = 0.f;
    for (int i = beg; i < end; ++i) {
        int e = perm[i];
        int c = cols[e];
        float v = vals[e], mv = mvals[e];
        float xv = xc[c * DD + lane];
        float yv = yc[c * DD + lane];
        ax = fmaf(v, xv, ax);
        ay = fmaf(mv, yv, ay);
    }
    int o = w * DD + lane;
    xn[o] = ax; yn[o] = ay;
    if (final_pass) {
        outx[o] = (outx[o] + ax) * 0.25f;
        outy[o] = (outy[o] + ay) * 0.25f;
    } else {
        outx[o] += ax;
        outy[o] += ay;
    }
}

__global__ void final_kernel(const double* __restrict__ gate_sum, float* __restrict__ out_scalar) {
    if (threadIdx.x == 0) out_scalar[0] = (float)(*gate_sum * (1.0 / (double)SS));
}

extern "C" void kernel_launch(void* const* d_in, const int* in_sizes, int n_in,
                              void* d_out, int out_size, void* d_ws, size_t ws_size,
                              hipStream_t stream) {
    const float* user = (const float*)d_in[0];
    const float* item = (const float*)d_in[1];
    const int*   rows = (const int*)d_in[2];
    const int*   cols = (const int*)d_in[3];
    const float* vals = (const float*)d_in[4];
    const int*   sidx = (const int*)d_in[5];
    const float* eps  = (const float*)d_in[6];
    const float* W1   = (const float*)d_in[7];
    const float* b1   = (const float*)d_in[8];
    const float* W2   = (const float*)d_in[9];
    const float* b2   = (const float*)d_in[10];

    float* out  = (float*)d_out;
    const size_t ND = (size_t)NN * DD;           // 9,600,000
    float* outx = out;
    float* outy = out + ND;
    float* out_scalar = out + 2 * ND;

    // workspace layout (aliased regions to stay <= ~165 MB):
    //   [0,4ND)         : x_cur, y_cur, x_next, y_next
    //   A = 4ND, 400000 : gate (phase 1)  -> rowptr[NN+1] + cursor[NN] (phase 2)
    //   B = A+400000, E : mvals
    //   C = B+E, E      : winner (phase 1) -> perm (phase 2)
    //   D = C+E         : bsum[NB_SCAN], then gate_sum (8B aligned)
    float* ws = (float*)d_ws;
    float* x_cur  = ws;
    float* y_cur  = ws + ND;
    float* x_next = ws + 2 * ND;
    float* y_next = ws + 3 * ND;
    float* regionA = ws + 4 * ND;
    float* gate   = regionA;                      // phase 1
    int*   rowptr = (int*)regionA;                // phase 2 (NN+1 ints)
    int*   cursor = (int*)regionA + 150016;       // phase 2 (NN ints); 300016 < 400000 ok
    float* mvals  = regionA + 400000;
    int*   winner = (int*)(mvals + EE);           // phase 1
    int*   perm   = winner;                       // phase 2 (alias)
    int*   bsum   = winner + EE;                  // NB_SCAN ints
    double* gate_sum = (double*)(((uintptr_t)(bsum + NB_SCAN) + 7) & ~(uintptr_t)7);

    const int B = 256;
    const int grid_ND = (int)((ND + B - 1) / B);
    const int grid_S  = (SS + B - 1) / B;
    const int grid_E  = (EE + B - 1) / B;
    const int grid_N  = (NN + B - 1) / B;         // == NB_SCAN
    const int grid_spmm = (int)((NN * 64 + B - 1) / B);

    init_kernel<<<grid_ND, B, 0, stream>>>(user, item, x_cur, y_cur, outx, outy,
                                           winner, gate_sum);
    gate_kernel<<<4096, B, 0, stream>>>(user, item, rows, cols, sidx, eps,
                                        W1, b1, W2, b2, gate, gate_sum);
    winner_kernel<<<grid_S, B, 0, stream>>>(sidx, winner);
    mvals_kernel<<<grid_E, B, 0, stream>>>(vals, winner, gate, mvals);
    // gate + winner now dead -> build CSR into their space
    deg_zero_kernel<<<grid_N, B, 0, stream>>>(cursor);
    hist_kernel<<<grid_E, B, 0, stream>>>(rows, cursor);
    scan1_kernel<<<NB_SCAN, 256, 0, stream>>>(cursor, rowptr, bsum);
    scan2_kernel<<<1, 1024, 0, stream>>>(bsum);
    scan3_kernel<<<grid_N, B, 0, stream>>>(rowptr, bsum, cursor);
    scatter_kernel<<<grid_E, B, 0, stream>>>(rows, rowptr, cursor, perm);

    float* xc = x_cur;  float* yc = y_cur;
    float* xn = x_next; float* yn = y_next;
    for (int l = 0; l < 3; ++l) {
        spmm_csr_kernel<<<grid_spmm, B, 0, stream>>>(rowptr, perm, cols, vals, mvals,
                                                     xc, yc, xn, yn, outx, outy,
                                                     (l == 2) ? 1 : 0);
        float* t;
        t = xc; xc = xn; xn = t;
        t = yc; yc = yn; yn = t;
    }
    final_kernel<<<1, 64, 0, stream>>>(gate_sum, out_scalar);
}

// Round 3
// 1085.474 us; speedup vs baseline: 2.3046x; 1.5278x over previous
//
#include <hip/hip_runtime.h>
#include <math.h>

#define NUM_USERS 100000
#define NUM_ITEMS 50000
#define NN 150000
#define DD 64
#define EE 1250000
#define SS 400000
#define TAU 0.2f
#define EDGE_BIAS 0.5f
#define NB_SCAN 586  // ceil(NN/256)

typedef __attribute__((ext_vector_type(8))) _Float16 f16x8;
typedef __attribute__((ext_vector_type(4))) float f32x4;

#define LDW 136  // 128 + 8 f16 pad -> 272B row stride, 16B aligned, ~2-way banks

// ---------------------------------------------------------------------------
// init: x_cur = y_cur = out_x = out_y = ego; winner = -1; gate_sum = 0
// ---------------------------------------------------------------------------
__global__ void init_kernel(const float* __restrict__ user, const float* __restrict__ item,
                            float* __restrict__ x_cur, float* __restrict__ y_cur,
                            float* __restrict__ outx, float* __restrict__ outy,
                            int* __restrict__ winner, double* __restrict__ gate_sum) {
    int i = blockIdx.x * blockDim.x + threadIdx.x;
    if (i < NN * DD) {
        float v = (i < NUM_USERS * DD) ? user[i] : item[i - NUM_USERS * DD];
        x_cur[i] = v; y_cur[i] = v;
        outx[i] = v;  outy[i] = v;
    }
    if (i < EE) winner[i] = -1;
    if (i == 0) *gate_sum = 0.0;
}

// ---------------------------------------------------------------------------
// gate MLP via f16 MFMA. Block = 256 thr = 4 waves; 64 samples per tile.
//  - sc[64][LDW]: cat rows (f16), staged by 4 thr/sample (32 f16 each)
//  - W1^T staged once to LDS, then held as 16 B-fragments in registers
//  - per wave: 16 samples, 4 n-tiles x 4 k-iters MFMA, epilogue relu/W2/
//    16-lane xor-reduce -> logit, gumbel-sigmoid, float4 gate store
// ---------------------------------------------------------------------------
__global__ __launch_bounds__(256) void gate_kernel(
        const float* __restrict__ user, const float* __restrict__ item,
        const int* __restrict__ rows, const int* __restrict__ cols,
        const int* __restrict__ sidx, const float* __restrict__ eps,
        const float* __restrict__ W1, const float* __restrict__ b1,
        const float* __restrict__ W2, const float* __restrict__ b2,
        float* __restrict__ gate, double* __restrict__ gate_sum) {
    __shared__ _Float16 sc[64 * LDW];
    __shared__ _Float16 swt[64 * LDW];
    __shared__ double sdq[4];

    const int t    = threadIdx.x;
    const int lane = t & 63;
    const int w    = t >> 6;       // wave in block
    const int col  = lane & 15;
    const int quad = lane >> 4;

    // stage W1^T: swt[n][k] = W1[k*64+n]
    for (int idx = t; idx < 8192; idx += 256) {
        int k = idx >> 6, n = idx & 63;
        swt[n * LDW + k] = (_Float16)W1[idx];
    }
    // b1 folded in via accumulator init? Reference: relu(cat@W1 + b1).
    // We add b1 in the epilogue per output dim n (uniform per n-tile/col).
    float b1v[4];
#pragma unroll
    for (int nt = 0; nt < 4; ++nt) b1v[nt] = b1[nt * 16 + col];
    float w2v[4];
#pragma unroll
    for (int nt = 0; nt < 4; ++nt) w2v[nt] = W2[nt * 16 + col];
    const float b2v = b2[0];
    __syncthreads();

    // B fragments: bfrag[nt][kk]; lane holds B[k=kk*32+quad*8+j][n=nt*16+col]
    f16x8 bfrag[4][4];
#pragma unroll
    for (int nt = 0; nt < 4; ++nt)
#pragma unroll
        for (int kk = 0; kk < 4; ++kk)
            bfrag[nt][kk] = *(const f16x8*)&swt[(nt * 16 + col) * LDW + kk * 32 + quad * 8];

    double partial = 0.0;
    const int sloc = t >> 2;     // staging: local sample 0..63
    const int part = t & 3;      // staging: 32-float chunk of the 128-float cat row

    for (int tile = blockIdx.x; tile < SS / 64; tile += gridDim.x) {
        const int s0 = tile * 64;
        __syncthreads();   // prior iteration's sc reads complete
        {
            const int s = s0 + sloc;
            const int e = sidx[s];
            const int node = (part < 2) ? rows[e] : cols[e];
            const float* src = (node < NUM_USERS) ? user + (size_t)node * 64
                                                  : item + (size_t)(node - NUM_USERS) * 64;
            src += (part & 1) * 32;
            f16x8* dst = (f16x8*)&sc[sloc * LDW + part * 32];
            const float4* s4 = (const float4*)src;
#pragma unroll
            for (int h = 0; h < 4; ++h) {
                float4 v0 = s4[2 * h], v1 = s4[2 * h + 1];
                f16x8 o;
                o[0] = (_Float16)v0.x; o[1] = (_Float16)v0.y;
                o[2] = (_Float16)v0.z; o[3] = (_Float16)v0.w;
                o[4] = (_Float16)v1.x; o[5] = (_Float16)v1.y;
                o[6] = (_Float16)v1.z; o[7] = (_Float16)v1.w;
                dst[h] = o;
            }
        }
        __syncthreads();

        f32x4 acc[4] = {};
        const _Float16* abase = &sc[(w * 16 + col) * LDW + quad * 8];
#pragma unroll
        for (int kk = 0; kk < 4; ++kk) {
            f16x8 a = *(const f16x8*)(abase + kk * 32);
#pragma unroll
            for (int nt = 0; nt < 4; ++nt)
                acc[nt] = __builtin_amdgcn_mfma_f32_16x16x32_f16(a, bfrag[nt][kk], acc[nt], 0, 0, 0);
        }

        // epilogue: h = relu(C[m][n] + b1[n]); partial over n: sum h*W2[n]
        float p[4];
#pragma unroll
        for (int r = 0; r < 4; ++r) {
            float sum = 0.f;
#pragma unroll
            for (int nt = 0; nt < 4; ++nt)
                sum = fmaf(fmaxf(acc[nt][r] + b1v[nt], 0.f), w2v[nt], sum);
#pragma unroll
            for (int off = 8; off >= 1; off >>= 1) sum += __shfl_xor(sum, off);
            p[r] = sum + b2v;
        }
        if (col == 0) {
            const int sb = s0 + w * 16 + quad * 4;  // rows m=quad*4+r
            float4 ev4 = *(const float4*)(eps + sb);
            float g4[4];
            const float evs[4] = {ev4.x, ev4.y, ev4.z, ev4.w};
#pragma unroll
            for (int r = 0; r < 4; ++r) {
                float ev  = evs[r] * (1.f - 2e-6f) + 1e-6f;
                float gum = logf(ev) - log1pf(-ev);
                float z   = (p[r] + gum) * (1.f / TAU);
                float g   = 1.f / (1.f + expf(-z)) + EDGE_BIAS;
                g4[r] = g;
                partial += (double)g;
            }
            *(float4*)(gate + sb) = make_float4(g4[0], g4[1], g4[2], g4[3]);
        }
    }

    // block-reduce gate sum
#pragma unroll
    for (int off = 32; off >= 1; off >>= 1) partial += __shfl_xor(partial, off);
    if (lane == 0) sdq[w] = partial;
    __syncthreads();
    if (t == 0) atomicAdd(gate_sum, sdq[0] + sdq[1] + sdq[2] + sdq[3]);
}

// ---------------------------------------------------------------------------
// numpy last-write-wins: winner[e] = max s with sidx[s]==e; then mvals
// ---------------------------------------------------------------------------
__global__ void winner_kernel(const int* __restrict__ sidx, int* __restrict__ winner) {
    int s = blockIdx.x * blockDim.x + threadIdx.x;
    if (s < SS) atomicMax(&winner[sidx[s]], s);
}

__global__ void mvals_kernel(const float* __restrict__ vals, const int* __restrict__ winner,
                             const float* __restrict__ gate, float* __restrict__ mvals) {
    int e = blockIdx.x * blockDim.x + threadIdx.x;
    if (e < EE) {
        int w = winner[e];
        float v = vals[e];
        mvals[e] = (w >= 0) ? v * gate[w] : v;
    }
}

// ---------------------------------------------------------------------------
// CSR build: zero deg -> histogram -> 3-kernel exclusive scan -> scatter perm
// ---------------------------------------------------------------------------
__global__ void deg_zero_kernel(int* __restrict__ deg) {
    int i = blockIdx.x * blockDim.x + threadIdx.x;
    if (i < NN) deg[i] = 0;
}

__global__ void hist_kernel(const int* __restrict__ rows, int* __restrict__ deg) {
    int e = blockIdx.x * blockDim.x + threadIdx.x;
    if (e < EE) atomicAdd(&deg[rows[e]], 1);
}

__global__ void scan1_kernel(const int* __restrict__ deg, int* __restrict__ rowptr,
                             int* __restrict__ bsum) {
    __shared__ int sh[256];
    int tid = threadIdx.x;
    int i = blockIdx.x * 256 + tid;
    int v = (i < NN) ? deg[i] : 0;
    sh[tid] = v;
    __syncthreads();
    for (int off = 1; off < 256; off <<= 1) {
        int t = (tid >= off) ? sh[tid - off] : 0;
        __syncthreads();
        sh[tid] += t;
        __syncthreads();
    }
    if (i < NN) rowptr[i] = sh[tid] - v;
    if (tid == 255) bsum[blockIdx.x] = sh[255];
}

__global__ void scan2_kernel(int* __restrict__ bsum) {
    __shared__ int sh[1024];
    int tid = threadIdx.x;
    int v = (tid < NB_SCAN) ? bsum[tid] : 0;
    sh[tid] = v;
    __syncthreads();
    for (int off = 1; off < 1024; off <<= 1) {
        int t = (tid >= off) ? sh[tid - off] : 0;
        __syncthreads();
        sh[tid] += t;
        __syncthreads();
    }
    if (tid < NB_SCAN) bsum[tid] = sh[tid] - v;
}

__global__ void scan3_kernel(int* __restrict__ rowptr, const int* __restrict__ bsum,
                             int* __restrict__ cursor) {
    int i = blockIdx.x * blockDim.x + threadIdx.x;
    if (i < NN) {
        rowptr[i] += bsum[i >> 8];
        cursor[i] = 0;
    }
    if (i == 0) rowptr[NN] = EE;
}

__global__ void scatter_kernel(const int* __restrict__ rows, const int* __restrict__ rowptr,
                               int* __restrict__ cursor, int* __restrict__ perm) {
    int e = blockIdx.x * blockDim.x + threadIdx.x;
    if (e < EE) {
        int r = rows[e];
        int pos = rowptr[r] + atomicAdd(&cursor[r], 1);
        perm[pos] = e;
    }
}

// ---------------------------------------------------------------------------
// gather-SpMM, dual chain, fold fused. One wave per row, lane = dim.
// ---------------------------------------------------------------------------
__global__ __launch_bounds__(256) void spmm_csr_kernel(
        const int* __restrict__ rowptr, const int* __restrict__ perm,
        const int* __restrict__ cols,
        const float* __restrict__ vals, const float* __restrict__ mvals,
        const float* __restrict__ xc, const float* __restrict__ yc,
        float* __restrict__ xn, float* __restrict__ yn,
        float* __restrict__ outx, float* __restrict__ outy, int final_pass) {
    int w = (blockIdx.x * blockDim.x + threadIdx.x) >> 6;
    int lane = threadIdx.x & 63;
    if (w >= NN) return;
    int beg = rowptr[w], end = rowptr[w + 1];
    float ax = 0.f, ay = 0.f;
    for (int i = beg; i < end; ++i) {
        int e = perm[i];
        int c = cols[e];
        float v = vals[e], mv = mvals[e];
        float xv = xc[c * DD + lane];
        float yv = yc[c * DD + lane];
        ax = fmaf(v, xv, ax);
        ay = fmaf(mv, yv, ay);
    }
    int o = w * DD + lane;
    xn[o] = ax; yn[o] = ay;
    if (final_pass) {
        outx[o] = (outx[o] + ax) * 0.25f;
        outy[o] = (outy[o] + ay) * 0.25f;
    } else {
        outx[o] += ax;
        outy[o] += ay;
    }
}

__global__ void final_kernel(const double* __restrict__ gate_sum, float* __restrict__ out_scalar) {
    if (threadIdx.x == 0) out_scalar[0] = (float)(*gate_sum * (1.0 / (double)SS));
}

extern "C" void kernel_launch(void* const* d_in, const int* in_sizes, int n_in,
                              void* d_out, int out_size, void* d_ws, size_t ws_size,
                              hipStream_t stream) {
    const float* user = (const float*)d_in[0];
    const float* item = (const float*)d_in[1];
    const int*   rows = (const int*)d_in[2];
    const int*   cols = (const int*)d_in[3];
    const float* vals = (const float*)d_in[4];
    const int*   sidx = (const int*)d_in[5];
    const float* eps  = (const float*)d_in[6];
    const float* W1   = (const float*)d_in[7];
    const float* b1   = (const float*)d_in[8];
    const float* W2   = (const float*)d_in[9];
    const float* b2   = (const float*)d_in[10];

    float* out  = (float*)d_out;
    const size_t ND = (size_t)NN * DD;
    float* outx = out;
    float* outy = out + ND;
    float* out_scalar = out + 2 * ND;

    // workspace layout (aliased; fits prior 165.2 MB footprint):
    //   [0,4ND)         : x_cur, y_cur, x_next, y_next
    //   A = 4ND, 400000 : gate (phase 1) -> rowptr[NN+1] + cursor[NN] (phase 2)
    //   B = A+400000, E : mvals
    //   C = B+E, E      : winner (phase 1) -> perm (phase 2)
    //   D = C+E         : bsum[NB_SCAN], then gate_sum (8B aligned)
    float* ws = (float*)d_ws;
    float* x_cur  = ws;
    float* y_cur  = ws + ND;
    float* x_next = ws + 2 * ND;
    float* y_next = ws + 3 * ND;
    float* regionA = ws + 4 * ND;
    float* gate   = regionA;
    int*   rowptr = (int*)regionA;
    int*   cursor = (int*)regionA + 150016;
    float* mvals  = regionA + 400000;
    int*   winner = (int*)(mvals + EE);
    int*   perm   = winner;
    int*   bsum   = winner + EE;
    double* gate_sum = (double*)(((uintptr_t)(bsum + NB_SCAN) + 7) & ~(uintptr_t)7);

    const int B = 256;
    const int grid_ND = (int)((ND + B - 1) / B);
    const int grid_S  = (SS + B - 1) / B;
    const int grid_E  = (EE + B - 1) / B;
    const int grid_N  = (NN + B - 1) / B;
    const int grid_spmm = (int)((NN * 64 + B - 1) / B);

    init_kernel<<<grid_ND, B, 0, stream>>>(user, item, x_cur, y_cur, outx, outy,
                                           winner, gate_sum);
    gate_kernel<<<2048, B, 0, stream>>>(user, item, rows, cols, sidx, eps,
                                        W1, b1, W2, b2, gate, gate_sum);
    winner_kernel<<<grid_S, B, 0, stream>>>(sidx, winner);
    mvals_kernel<<<grid_E, B, 0, stream>>>(vals, winner, gate, mvals);
    deg_zero_kernel<<<grid_N, B, 0, stream>>>(cursor);
    hist_kernel<<<grid_E, B, 0, stream>>>(rows, cursor);
    scan1_kernel<<<NB_SCAN, 256, 0, stream>>>(cursor, rowptr, bsum);
    scan2_kernel<<<1, 1024, 0, stream>>>(bsum);
    scan3_kernel<<<grid_N, B, 0, stream>>>(rowptr, bsum, cursor);
    scatter_kernel<<<grid_E, B, 0, stream>>>(rows, rowptr, cursor, perm);

    float* xc = x_cur;  float* yc = y_cur;
    float* xn = x_next; float* yn = y_next;
    for (int l = 0; l < 3; ++l) {
        spmm_csr_kernel<<<grid_spmm, B, 0, stream>>>(rowptr, perm, cols, vals, mvals,
                                                     xc, yc, xn, yn, outx, outy,
                                                     (l == 2) ? 1 : 0);
        float* t;
        t = xc; xc = xn; xn = t;
        t = yc; yc = yn; yn = t;
    }
    final_kernel<<<1, 64, 0, stream>>>(gate_sum, out_scalar);
}

// Round 4
// 786.629 us; speedup vs baseline: 3.1801x; 1.3799x over previous
//
#include <hip/hip_runtime.h>
#include <math.h>

#define NUM_USERS 100000
#define NUM_ITEMS 50000
#define NN 150000
#define DD 64
#define EE 1250000
#define SS 400000
#define TAU 0.2f
#define EDGE_BIAS 0.5f
#define NB_SCAN 586  // ceil(NN/256)

typedef __attribute__((ext_vector_type(8))) _Float16 f16x8;
typedef __attribute__((ext_vector_type(4))) float f32x4;

#define LDW 136  // f16 LDS row stride for gate kernel

// bf16 helpers (RNE, finite inputs)
__device__ __forceinline__ unsigned int pack_bf16(float lo, float hi) {
    unsigned int a = __float_as_uint(lo), b = __float_as_uint(hi);
    a += 0x7fffu + ((a >> 16) & 1u);
    b += 0x7fffu + ((b >> 16) & 1u);
    return (a >> 16) | (b & 0xffff0000u);
}
__device__ __forceinline__ float bf_lo(unsigned int u) { return __uint_as_float(u << 16); }
__device__ __forceinline__ float bf_hi(unsigned int u) { return __uint_as_float(u & 0xffff0000u); }

// ---------------------------------------------------------------------------
// init: z0[n][d] = bf16 pair of ego[n][2(d&31)], both chains identical at l=0.
// also winner=-1, gate_sum=0.
// ---------------------------------------------------------------------------
__global__ void init_kernel(const float* __restrict__ user, const float* __restrict__ item,
                            unsigned int* __restrict__ z0,
                            int* __restrict__ winner, double* __restrict__ gate_sum) {
    int j = blockIdx.x * blockDim.x + threadIdx.x;
    if (j < NN * DD) {
        int n = j >> 6, d = j & 63, dp = d & 31;
        const float* ego = (n < NUM_USERS) ? user + (size_t)n * 64
                                           : item + (size_t)(n - NUM_USERS) * 64;
        float2 e = *(const float2*)(ego + 2 * dp);
        z0[j] = pack_bf16(e.x, e.y);
    }
    if (j < EE) winner[j] = -1;
    if (j == 0) *gate_sum = 0.0;
}

// ---------------------------------------------------------------------------
// gate MLP via f16 MFMA (unchanged from R2)
// ---------------------------------------------------------------------------
__global__ __launch_bounds__(256) void gate_kernel(
        const float* __restrict__ user, const float* __restrict__ item,
        const int* __restrict__ rows, const int* __restrict__ cols,
        const int* __restrict__ sidx, const float* __restrict__ eps,
        const float* __restrict__ W1, const float* __restrict__ b1,
        const float* __restrict__ W2, const float* __restrict__ b2,
        float* __restrict__ gate, double* __restrict__ gate_sum) {
    __shared__ _Float16 sc[64 * LDW];
    __shared__ _Float16 swt[64 * LDW];
    __shared__ double sdq[4];

    const int t    = threadIdx.x;
    const int lane = t & 63;
    const int w    = t >> 6;
    const int col  = lane & 15;
    const int quad = lane >> 4;

    for (int idx = t; idx < 8192; idx += 256) {
        int k = idx >> 6, n = idx & 63;
        swt[n * LDW + k] = (_Float16)W1[idx];
    }
    float b1v[4];
#pragma unroll
    for (int nt = 0; nt < 4; ++nt) b1v[nt] = b1[nt * 16 + col];
    float w2v[4];
#pragma unroll
    for (int nt = 0; nt < 4; ++nt) w2v[nt] = W2[nt * 16 + col];
    const float b2v = b2[0];
    __syncthreads();

    f16x8 bfrag[4][4];
#pragma unroll
    for (int nt = 0; nt < 4; ++nt)
#pragma unroll
        for (int kk = 0; kk < 4; ++kk)
            bfrag[nt][kk] = *(const f16x8*)&swt[(nt * 16 + col) * LDW + kk * 32 + quad * 8];

    double partial = 0.0;
    const int sloc = t >> 2;
    const int part = t & 3;

    for (int tile = blockIdx.x; tile < SS / 64; tile += gridDim.x) {
        const int s0 = tile * 64;
        __syncthreads();
        {
            const int s = s0 + sloc;
            const int e = sidx[s];
            const int node = (part < 2) ? rows[e] : cols[e];
            const float* src = (node < NUM_USERS) ? user + (size_t)node * 64
                                                  : item + (size_t)(node - NUM_USERS) * 64;
            src += (part & 1) * 32;
            f16x8* dst = (f16x8*)&sc[sloc * LDW + part * 32];
            const float4* s4 = (const float4*)src;
#pragma unroll
            for (int h = 0; h < 4; ++h) {
                float4 v0 = s4[2 * h], v1 = s4[2 * h + 1];
                f16x8 o;
                o[0] = (_Float16)v0.x; o[1] = (_Float16)v0.y;
                o[2] = (_Float16)v0.z; o[3] = (_Float16)v0.w;
                o[4] = (_Float16)v1.x; o[5] = (_Float16)v1.y;
                o[6] = (_Float16)v1.z; o[7] = (_Float16)v1.w;
                dst[h] = o;
            }
        }
        __syncthreads();

        f32x4 acc[4] = {};
        const _Float16* abase = &sc[(w * 16 + col) * LDW + quad * 8];
#pragma unroll
        for (int kk = 0; kk < 4; ++kk) {
            f16x8 a = *(const f16x8*)(abase + kk * 32);
#pragma unroll
            for (int nt = 0; nt < 4; ++nt)
                acc[nt] = __builtin_amdgcn_mfma_f32_16x16x32_f16(a, bfrag[nt][kk], acc[nt], 0, 0, 0);
        }

        float p[4];
#pragma unroll
        for (int r = 0; r < 4; ++r) {
            float sum = 0.f;
#pragma unroll
            for (int nt = 0; nt < 4; ++nt)
                sum = fmaf(fmaxf(acc[nt][r] + b1v[nt], 0.f), w2v[nt], sum);
#pragma unroll
            for (int off = 8; off >= 1; off >>= 1) sum += __shfl_xor(sum, off);
            p[r] = sum + b2v;
        }
        if (col == 0) {
            const int sb = s0 + w * 16 + quad * 4;
            float4 ev4 = *(const float4*)(eps + sb);
            float g4[4];
            const float evs[4] = {ev4.x, ev4.y, ev4.z, ev4.w};
#pragma unroll
            for (int r = 0; r < 4; ++r) {
                float ev  = evs[r] * (1.f - 2e-6f) + 1e-6f;
                float gum = logf(ev) - log1pf(-ev);
                float z   = (p[r] + gum) * (1.f / TAU);
                float g   = 1.f / (1.f + expf(-z)) + EDGE_BIAS;
                g4[r] = g;
                partial += (double)g;
            }
            *(float4*)(gate + sb) = make_float4(g4[0], g4[1], g4[2], g4[3]);
        }
    }

#pragma unroll
    for (int off = 32; off >= 1; off >>= 1) partial += __shfl_xor(partial, off);
    if (lane == 0) sdq[w] = partial;
    __syncthreads();
    if (t == 0) atomicAdd(gate_sum, sdq[0] + sdq[1] + sdq[2] + sdq[3]);
}

// ---------------------------------------------------------------------------
// numpy last-write-wins + masked values
// ---------------------------------------------------------------------------
__global__ void winner_kernel(const int* __restrict__ sidx, int* __restrict__ winner) {
    int s = blockIdx.x * blockDim.x + threadIdx.x;
    if (s < SS) atomicMax(&winner[sidx[s]], s);
}

__global__ void mvals_kernel(const float* __restrict__ vals, const int* __restrict__ winner,
                             const float* __restrict__ gate, float* __restrict__ mvals) {
    int e = blockIdx.x * blockDim.x + threadIdx.x;
    if (e < EE) {
        int w = winner[e];
        float v = vals[e];
        mvals[e] = (w >= 0) ? v * gate[w] : v;
    }
}

// ---------------------------------------------------------------------------
// CSR build
// ---------------------------------------------------------------------------
__global__ void deg_zero_kernel(int* __restrict__ deg) {
    int i = blockIdx.x * blockDim.x + threadIdx.x;
    if (i < NN) deg[i] = 0;
}

__global__ void hist_kernel(const int* __restrict__ rows, int* __restrict__ deg) {
    int e = blockIdx.x * blockDim.x + threadIdx.x;
    if (e < EE) atomicAdd(&deg[rows[e]], 1);
}

__global__ void scan1_kernel(const int* __restrict__ deg, int* __restrict__ rowptr,
                             int* __restrict__ bsum) {
    __shared__ int sh[256];
    int tid = threadIdx.x;
    int i = blockIdx.x * 256 + tid;
    int v = (i < NN) ? deg[i] : 0;
    sh[tid] = v;
    __syncthreads();
    for (int off = 1; off < 256; off <<= 1) {
        int t = (tid >= off) ? sh[tid - off] : 0;
        __syncthreads();
        sh[tid] += t;
        __syncthreads();
    }
    if (i < NN) rowptr[i] = sh[tid] - v;
    if (tid == 255) bsum[blockIdx.x] = sh[255];
}

__global__ void scan2_kernel(int* __restrict__ bsum) {
    __shared__ int sh[1024];
    int tid = threadIdx.x;
    int v = (tid < NB_SCAN) ? bsum[tid] : 0;
    sh[tid] = v;
    __syncthreads();
    for (int off = 1; off < 1024; off <<= 1) {
        int t = (tid >= off) ? sh[tid - off] : 0;
        __syncthreads();
        sh[tid] += t;
        __syncthreads();
    }
    if (tid < NB_SCAN) bsum[tid] = sh[tid] - v;
}

__global__ void scan3_kernel(int* __restrict__ rowptr, const int* __restrict__ bsum,
                             int* __restrict__ cursor) {
    int i = blockIdx.x * blockDim.x + threadIdx.x;
    if (i < NN) {
        rowptr[i] += bsum[i >> 8];
        cursor[i] = 0;
    }
    if (i == 0) rowptr[NN] = EE;
}

// scatter now pre-joins edge payload into CSR order: {col, val, mval, pad}
__global__ void scatter_kernel(const int* __restrict__ rows, const int* __restrict__ cols,
                               const float* __restrict__ vals, const float* __restrict__ mvals,
                               const int* __restrict__ rowptr,
                               int* __restrict__ cursor, int4* __restrict__ edata) {
    int e = blockIdx.x * blockDim.x + threadIdx.x;
    if (e < EE) {
        int r = rows[e];
        int pos = rowptr[r] + atomicAdd(&cursor[r], 1);
        edata[pos] = make_int4(cols[e], __float_as_int(vals[e]), __float_as_int(mvals[e]), 0);
    }
}

// ---------------------------------------------------------------------------
// packed dual-chain gather-SpMM: one wave per row; lane<32 = x chain dims
// (2*lane, 2*lane+1), lane>=32 = y chain. One 256B gather per edge.
// ---------------------------------------------------------------------------
__global__ __launch_bounds__(256) void spmm_packed_kernel(
        const int* __restrict__ rowptr, const int4* __restrict__ edata,
        const unsigned int* __restrict__ zin, unsigned int* __restrict__ zout) {
    int w = (blockIdx.x * blockDim.x + threadIdx.x) >> 6;
    int lane = threadIdx.x & 63;
    if (w >= NN) return;
    int beg = rowptr[w], end = rowptr[w + 1];
    float a0 = 0.f, a1 = 0.f;
    for (int i = beg; i < end; ++i) {
        int4 ed = edata[i];                       // wave-uniform sequential
        unsigned int zp = zin[(size_t)ed.x * 64 + lane];
        float wgt = (lane < 32) ? __int_as_float(ed.y) : __int_as_float(ed.z);
        a0 = fmaf(wgt, bf_lo(zp), a0);
        a1 = fmaf(wgt, bf_hi(zp), a1);
    }
    zout[(size_t)w * 64 + lane] = pack_bf16(a0, a1);
}

// ---------------------------------------------------------------------------
// fold: out = (ego + l1 + l2 + l3) / 4, split x->outx, y->outy
// ---------------------------------------------------------------------------
__global__ void fold_kernel(const float* __restrict__ user, const float* __restrict__ item,
                            const unsigned int* __restrict__ z1,
                            const unsigned int* __restrict__ z2,
                            const unsigned int* __restrict__ z3,
                            float* __restrict__ outx, float* __restrict__ outy) {
    int j = blockIdx.x * blockDim.x + threadIdx.x;
    if (j >= NN * DD) return;
    int n = j >> 6, d = j & 63, dp = d & 31;
    const float* ego = (n < NUM_USERS) ? user + (size_t)n * 64
                                       : item + (size_t)(n - NUM_USERS) * 64;
    float2 e = *(const float2*)(ego + 2 * dp);
    unsigned int u1 = z1[j], u2 = z2[j], u3 = z3[j];
    float s0 = e.x + bf_lo(u1) + bf_lo(u2) + bf_lo(u3);
    float s1 = e.y + bf_hi(u1) + bf_hi(u2) + bf_hi(u3);
    float* dst = ((d < 32) ? outx : outy) + (size_t)n * 64 + 2 * dp;
    *(float2*)dst = make_float2(s0 * 0.25f, s1 * 0.25f);
}

__global__ void final_kernel(const double* __restrict__ gate_sum, float* __restrict__ out_scalar) {
    if (threadIdx.x == 0) out_scalar[0] = (float)(*gate_sum * (1.0 / (double)SS));
}

extern "C" void kernel_launch(void* const* d_in, const int* in_sizes, int n_in,
                              void* d_out, int out_size, void* d_ws, size_t ws_size,
                              hipStream_t stream) {
    const float* user = (const float*)d_in[0];
    const float* item = (const float*)d_in[1];
    const int*   rows = (const int*)d_in[2];
    const int*   cols = (const int*)d_in[3];
    const float* vals = (const float*)d_in[4];
    const int*   sidx = (const int*)d_in[5];
    const float* eps  = (const float*)d_in[6];
    const float* W1   = (const float*)d_in[7];
    const float* b1   = (const float*)d_in[8];
    const float* W2   = (const float*)d_in[9];
    const float* b2   = (const float*)d_in[10];

    float* out  = (float*)d_out;
    const size_t ND = (size_t)NN * DD;           // 9.6M
    float* outx = out;
    float* outy = out + ND;
    float* out_scalar = out + 2 * ND;

    // workspace (uints), total ~147 MB:
    //   z[0] @ 0       (38.4 MB)  ego bf16 packed; reused as z3
    //   z[1] @ ND      (38.4 MB)
    //   z[2] @ 2ND     (38.4 MB)
    //   edata @ 3ND    (20 MB, int4 x EE)
    //   regionA @ 3ND+5M : gate[SS] (phase1) -> rowptr[NN+1]+cursor[NN] (phase2)
    //   mvals  @ +400000 (5 MB)
    //   winner @ +EE     (5 MB)
    //   bsum, gate_sum
    unsigned int* wsu = (unsigned int*)d_ws;
    unsigned int* z0 = wsu;
    unsigned int* z1 = wsu + ND;
    unsigned int* z2 = wsu + 2 * ND;
    int4* edata = (int4*)(wsu + 3 * ND);
    unsigned int* regionA = wsu + 3 * ND + (size_t)EE * 4;
    float* gate   = (float*)regionA;
    int*   rowptr = (int*)regionA;
    int*   cursor = (int*)regionA + 150016;
    float* mvals  = (float*)(regionA + 400000);
    int*   winner = (int*)(regionA + 400000 + EE);
    int*   bsum   = winner + EE;
    double* gate_sum = (double*)(((uintptr_t)(bsum + NB_SCAN) + 7) & ~(uintptr_t)7);

    const int B = 256;
    const int grid_ND = (int)((ND + B - 1) / B);
    const int grid_S  = (SS + B - 1) / B;
    const int grid_E  = (EE + B - 1) / B;
    const int grid_N  = (NN + B - 1) / B;
    const int grid_spmm = (int)((NN * 64 + B - 1) / B);

    init_kernel<<<grid_ND, B, 0, stream>>>(user, item, z0, winner, gate_sum);
    gate_kernel<<<2048, B, 0, stream>>>(user, item, rows, cols, sidx, eps,
                                        W1, b1, W2, b2, gate, gate_sum);
    winner_kernel<<<grid_S, B, 0, stream>>>(sidx, winner);
    mvals_kernel<<<grid_E, B, 0, stream>>>(vals, winner, gate, mvals);
    deg_zero_kernel<<<grid_N, B, 0, stream>>>(cursor);
    hist_kernel<<<grid_E, B, 0, stream>>>(rows, cursor);
    scan1_kernel<<<NB_SCAN, 256, 0, stream>>>(cursor, rowptr, bsum);
    scan2_kernel<<<1, 1024, 0, stream>>>(bsum);
    scan3_kernel<<<grid_N, B, 0, stream>>>(rowptr, bsum, cursor);
    scatter_kernel<<<grid_E, B, 0, stream>>>(rows, cols, vals, mvals, rowptr, cursor, edata);

    // layer chain: z0 -> z1 -> z2 -> z3(=z0 space)
    spmm_packed_kernel<<<grid_spmm, B, 0, stream>>>(rowptr, edata, z0, z1);
    spmm_packed_kernel<<<grid_spmm, B, 0, stream>>>(rowptr, edata, z1, z2);
    spmm_packed_kernel<<<grid_spmm, B, 0, stream>>>(rowptr, edata, z2, z0);

    fold_kernel<<<grid_ND, B, 0, stream>>>(user, item, z1, z2, z0, outx, outy);
    final_kernel<<<1, 64, 0, stream>>>(gate_sum, out_scalar);
}

// Round 5
// 618.789 us; speedup vs baseline: 4.0426x; 1.2712x over previous
//
#include <hip/hip_runtime.h>
#include <math.h>

#define NUM_USERS 100000
#define NUM_ITEMS 50000
#define NN 150000
#define DD 64
#define EE 1250000
#define SS 400000
#define TAU 0.2f
#define EDGE_BIAS 0.5f
#define NB_SCAN 586  // ceil(NN/256)

typedef __attribute__((ext_vector_type(8))) _Float16 f16x8;
typedef __attribute__((ext_vector_type(4))) float f32x4;

#define LDW 136  // f16 LDS row stride for gate kernel

// bf16 helpers (RNE, finite inputs)
__device__ __forceinline__ unsigned int pack_bf16(float lo, float hi) {
    unsigned int a = __float_as_uint(lo), b = __float_as_uint(hi);
    a += 0x7fffu + ((a >> 16) & 1u);
    b += 0x7fffu + ((b >> 16) & 1u);
    return (a >> 16) | (b & 0xffff0000u);
}
__device__ __forceinline__ float bf_lo(unsigned int u) { return __uint_as_float(u << 16); }
__device__ __forceinline__ float bf_hi(unsigned int u) { return __uint_as_float(u & 0xffff0000u); }

// ---------------------------------------------------------------------------
// init: z0[n][d] = bf16 pair of ego[n][2(d&31)], both chains identical at l=0.
// ---------------------------------------------------------------------------
__global__ void init_kernel(const float* __restrict__ user, const float* __restrict__ item,
                            unsigned int* __restrict__ z0,
                            int* __restrict__ winner, double* __restrict__ gate_sum) {
    int j = blockIdx.x * blockDim.x + threadIdx.x;
    if (j < NN * DD) {
        int n = j >> 6, d = j & 63, dp = d & 31;
        const float* ego = (n < NUM_USERS) ? user + (size_t)n * 64
                                           : item + (size_t)(n - NUM_USERS) * 64;
        float2 e = *(const float2*)(ego + 2 * dp);
        z0[j] = pack_bf16(e.x, e.y);
    }
    if (j < EE) winner[j] = -1;
    if (j == 0) *gate_sum = 0.0;
}

// ---------------------------------------------------------------------------
// gate MLP via f16 MFMA (unchanged)
// ---------------------------------------------------------------------------
__global__ __launch_bounds__(256) void gate_kernel(
        const float* __restrict__ user, const float* __restrict__ item,
        const int* __restrict__ rows, const int* __restrict__ cols,
        const int* __restrict__ sidx, const float* __restrict__ eps,
        const float* __restrict__ W1, const float* __restrict__ b1,
        const float* __restrict__ W2, const float* __restrict__ b2,
        float* __restrict__ gate, double* __restrict__ gate_sum) {
    __shared__ _Float16 sc[64 * LDW];
    __shared__ _Float16 swt[64 * LDW];
    __shared__ double sdq[4];

    const int t    = threadIdx.x;
    const int lane = t & 63;
    const int w    = t >> 6;
    const int col  = lane & 15;
    const int quad = lane >> 4;

    for (int idx = t; idx < 8192; idx += 256) {
        int k = idx >> 6, n = idx & 63;
        swt[n * LDW + k] = (_Float16)W1[idx];
    }
    float b1v[4];
#pragma unroll
    for (int nt = 0; nt < 4; ++nt) b1v[nt] = b1[nt * 16 + col];
    float w2v[4];
#pragma unroll
    for (int nt = 0; nt < 4; ++nt) w2v[nt] = W2[nt * 16 + col];
    const float b2v = b2[0];
    __syncthreads();

    f16x8 bfrag[4][4];
#pragma unroll
    for (int nt = 0; nt < 4; ++nt)
#pragma unroll
        for (int kk = 0; kk < 4; ++kk)
            bfrag[nt][kk] = *(const f16x8*)&swt[(nt * 16 + col) * LDW + kk * 32 + quad * 8];

    double partial = 0.0;
    const int sloc = t >> 2;
    const int part = t & 3;

    for (int tile = blockIdx.x; tile < SS / 64; tile += gridDim.x) {
        const int s0 = tile * 64;
        __syncthreads();
        {
            const int s = s0 + sloc;
            const int e = sidx[s];
            const int node = (part < 2) ? rows[e] : cols[e];
            const float* src = (node < NUM_USERS) ? user + (size_t)node * 64
                                                  : item + (size_t)(node - NUM_USERS) * 64;
            src += (part & 1) * 32;
            f16x8* dst = (f16x8*)&sc[sloc * LDW + part * 32];
            const float4* s4 = (const float4*)src;
#pragma unroll
            for (int h = 0; h < 4; ++h) {
                float4 v0 = s4[2 * h], v1 = s4[2 * h + 1];
                f16x8 o;
                o[0] = (_Float16)v0.x; o[1] = (_Float16)v0.y;
                o[2] = (_Float16)v0.z; o[3] = (_Float16)v0.w;
                o[4] = (_Float16)v1.x; o[5] = (_Float16)v1.y;
                o[6] = (_Float16)v1.z; o[7] = (_Float16)v1.w;
                dst[h] = o;
            }
        }
        __syncthreads();

        f32x4 acc[4] = {};
        const _Float16* abase = &sc[(w * 16 + col) * LDW + quad * 8];
#pragma unroll
        for (int kk = 0; kk < 4; ++kk) {
            f16x8 a = *(const f16x8*)(abase + kk * 32);
#pragma unroll
            for (int nt = 0; nt < 4; ++nt)
                acc[nt] = __builtin_amdgcn_mfma_f32_16x16x32_f16(a, bfrag[nt][kk], acc[nt], 0, 0, 0);
        }

        float p[4];
#pragma unroll
        for (int r = 0; r < 4; ++r) {
            float sum = 0.f;
#pragma unroll
            for (int nt = 0; nt < 4; ++nt)
                sum = fmaf(fmaxf(acc[nt][r] + b1v[nt], 0.f), w2v[nt], sum);
#pragma unroll
            for (int off = 8; off >= 1; off >>= 1) sum += __shfl_xor(sum, off);
            p[r] = sum + b2v;
        }
        if (col == 0) {
            const int sb = s0 + w * 16 + quad * 4;
            float4 ev4 = *(const float4*)(eps + sb);
            float g4[4];
            const float evs[4] = {ev4.x, ev4.y, ev4.z, ev4.w};
#pragma unroll
            for (int r = 0; r < 4; ++r) {
                float ev  = evs[r] * (1.f - 2e-6f) + 1e-6f;
                float gum = logf(ev) - log1pf(-ev);
                float z   = (p[r] + gum) * (1.f / TAU);
                float g   = 1.f / (1.f + expf(-z)) + EDGE_BIAS;
                g4[r] = g;
                partial += (double)g;
            }
            *(float4*)(gate + sb) = make_float4(g4[0], g4[1], g4[2], g4[3]);
        }
    }

#pragma unroll
    for (int off = 32; off >= 1; off >>= 1) partial += __shfl_xor(partial, off);
    if (lane == 0) sdq[w] = partial;
    __syncthreads();
    if (t == 0) atomicAdd(gate_sum, sdq[0] + sdq[1] + sdq[2] + sdq[3]);
}

// ---------------------------------------------------------------------------
// numpy last-write-wins + masked values
// ---------------------------------------------------------------------------
__global__ void winner_kernel(const int* __restrict__ sidx, int* __restrict__ winner) {
    int s = blockIdx.x * blockDim.x + threadIdx.x;
    if (s < SS) atomicMax(&winner[sidx[s]], s);
}

__global__ void mvals_kernel(const float* __restrict__ vals, const int* __restrict__ winner,
                             const float* __restrict__ gate, float* __restrict__ mvals) {
    int e = blockIdx.x * blockDim.x + threadIdx.x;
    if (e < EE) {
        int w = winner[e];
        float v = vals[e];
        mvals[e] = (w >= 0) ? v * gate[w] : v;
    }
}

// ---------------------------------------------------------------------------
// CSR build
// ---------------------------------------------------------------------------
__global__ void deg_zero_kernel(int* __restrict__ deg) {
    int i = blockIdx.x * blockDim.x + threadIdx.x;
    if (i < NN) deg[i] = 0;
}

__global__ void hist_kernel(const int* __restrict__ rows, int* __restrict__ deg) {
    int e = blockIdx.x * blockDim.x + threadIdx.x;
    if (e < EE) atomicAdd(&deg[rows[e]], 1);
}

__global__ void scan1_kernel(const int* __restrict__ deg, int* __restrict__ rowptr,
                             int* __restrict__ bsum) {
    __shared__ int sh[256];
    int tid = threadIdx.x;
    int i = blockIdx.x * 256 + tid;
    int v = (i < NN) ? deg[i] : 0;
    sh[tid] = v;
    __syncthreads();
    for (int off = 1; off < 256; off <<= 1) {
        int t = (tid >= off) ? sh[tid - off] : 0;
        __syncthreads();
        sh[tid] += t;
        __syncthreads();
    }
    if (i < NN) rowptr[i] = sh[tid] - v;
    if (tid == 255) bsum[blockIdx.x] = sh[255];
}

__global__ void scan2_kernel(int* __restrict__ bsum) {
    __shared__ int sh[1024];
    int tid = threadIdx.x;
    int v = (tid < NB_SCAN) ? bsum[tid] : 0;
    sh[tid] = v;
    __syncthreads();
    for (int off = 1; off < 1024; off <<= 1) {
        int t = (tid >= off) ? sh[tid - off] : 0;
        __syncthreads();
        sh[tid] += t;
        __syncthreads();
    }
    if (tid < NB_SCAN) bsum[tid] = sh[tid] - v;
}

__global__ void scan3_kernel(int* __restrict__ rowptr, const int* __restrict__ bsum,
                             int* __restrict__ cursor) {
    int i = blockIdx.x * blockDim.x + threadIdx.x;
    if (i < NN) {
        rowptr[i] += bsum[i >> 8];
        cursor[i] = 0;
    }
    if (i == 0) rowptr[NN] = EE;
}

// scatter pre-joins edge payload into CSR order: {col, val, mval, pad}
__global__ void scatter_kernel(const int* __restrict__ rows, const int* __restrict__ cols,
                               const float* __restrict__ vals, const float* __restrict__ mvals,
                               const int* __restrict__ rowptr,
                               int* __restrict__ cursor, int4* __restrict__ edata) {
    int e = blockIdx.x * blockDim.x + threadIdx.x;
    if (e < EE) {
        int r = rows[e];
        int pos = rowptr[r] + atomicAdd(&cursor[r], 1);
        edata[pos] = make_int4(cols[e], __float_as_int(vals[e]), __float_as_int(mvals[e]), 0);
    }
}

// ---------------------------------------------------------------------------
// packed dual-chain gather-SpMM, 4-way unrolled for memory-level parallelism.
// One wave per row; lane<32 = x chain, lane>=32 = y chain; 256B gather/edge.
// ---------------------------------------------------------------------------
__global__ __launch_bounds__(256) void spmm_packed_kernel(
        const int* __restrict__ rowptr, const int4* __restrict__ edata,
        const unsigned int* __restrict__ zin, unsigned int* __restrict__ zout) {
    int w = (blockIdx.x * blockDim.x + threadIdx.x) >> 6;
    int lane = threadIdx.x & 63;
    if (w >= NN) return;
    int beg = rowptr[w], end = rowptr[w + 1];
    float a0 = 0.f, a1 = 0.f;
    int i = beg;
    for (; i + 4 <= end; i += 4) {
        int4 e0 = edata[i + 0];
        int4 e1 = edata[i + 1];
        int4 e2 = edata[i + 2];
        int4 e3 = edata[i + 3];
        unsigned int p0 = zin[(size_t)e0.x * 64 + lane];
        unsigned int p1 = zin[(size_t)e1.x * 64 + lane];
        unsigned int p2 = zin[(size_t)e2.x * 64 + lane];
        unsigned int p3 = zin[(size_t)e3.x * 64 + lane];
        float w0 = (lane < 32) ? __int_as_float(e0.y) : __int_as_float(e0.z);
        float w1 = (lane < 32) ? __int_as_float(e1.y) : __int_as_float(e1.z);
        float w2 = (lane < 32) ? __int_as_float(e2.y) : __int_as_float(e2.z);
        float w3 = (lane < 32) ? __int_as_float(e3.y) : __int_as_float(e3.z);
        a0 = fmaf(w0, bf_lo(p0), a0); a1 = fmaf(w0, bf_hi(p0), a1);
        a0 = fmaf(w1, bf_lo(p1), a0); a1 = fmaf(w1, bf_hi(p1), a1);
        a0 = fmaf(w2, bf_lo(p2), a0); a1 = fmaf(w2, bf_hi(p2), a1);
        a0 = fmaf(w3, bf_lo(p3), a0); a1 = fmaf(w3, bf_hi(p3), a1);
    }
    for (; i < end; ++i) {
        int4 ed = edata[i];
        unsigned int zp = zin[(size_t)ed.x * 64 + lane];
        float wgt = (lane < 32) ? __int_as_float(ed.y) : __int_as_float(ed.z);
        a0 = fmaf(wgt, bf_lo(zp), a0);
        a1 = fmaf(wgt, bf_hi(zp), a1);
    }
    zout[(size_t)w * 64 + lane] = pack_bf16(a0, a1);
}

// ---------------------------------------------------------------------------
// fold: out = (ego + l1 + l2 + l3) / 4, split x->outx, y->outy
// ---------------------------------------------------------------------------
__global__ void fold_kernel(const float* __restrict__ user, const float* __restrict__ item,
                            const unsigned int* __restrict__ z1,
                            const unsigned int* __restrict__ z2,
                            const unsigned int* __restrict__ z3,
                            float* __restrict__ outx, float* __restrict__ outy) {
    int j = blockIdx.x * blockDim.x + threadIdx.x;
    if (j >= NN * DD) return;
    int n = j >> 6, d = j & 63, dp = d & 31;
    const float* ego = (n < NUM_USERS) ? user + (size_t)n * 64
                                       : item + (size_t)(n - NUM_USERS) * 64;
    float2 e = *(const float2*)(ego + 2 * dp);
    unsigned int u1 = z1[j], u2 = z2[j], u3 = z3[j];
    float s0 = e.x + bf_lo(u1) + bf_lo(u2) + bf_lo(u3);
    float s1 = e.y + bf_hi(u1) + bf_hi(u2) + bf_hi(u3);
    float* dst = ((d < 32) ? outx : outy) + (size_t)n * 64 + 2 * dp;
    *(float2*)dst = make_float2(s0 * 0.25f, s1 * 0.25f);
}

__global__ void final_kernel(const double* __restrict__ gate_sum, float* __restrict__ out_scalar) {
    if (threadIdx.x == 0) out_scalar[0] = (float)(*gate_sum * (1.0 / (double)SS));
}

extern "C" void kernel_launch(void* const* d_in, const int* in_sizes, int n_in,
                              void* d_out, int out_size, void* d_ws, size_t ws_size,
                              hipStream_t stream) {
    const float* user = (const float*)d_in[0];
    const float* item = (const float*)d_in[1];
    const int*   rows = (const int*)d_in[2];
    const int*   cols = (const int*)d_in[3];
    const float* vals = (const float*)d_in[4];
    const int*   sidx = (const int*)d_in[5];
    const float* eps  = (const float*)d_in[6];
    const float* W1   = (const float*)d_in[7];
    const float* b1   = (const float*)d_in[8];
    const float* W2   = (const float*)d_in[9];
    const float* b2   = (const float*)d_in[10];

    float* out  = (float*)d_out;
    const size_t ND = (size_t)NN * DD;
    float* outx = out;
    float* outy = out + ND;
    float* out_scalar = out + 2 * ND;

    unsigned int* wsu = (unsigned int*)d_ws;
    unsigned int* z0 = wsu;
    unsigned int* z1 = wsu + ND;
    unsigned int* z2 = wsu + 2 * ND;
    int4* edata = (int4*)(wsu + 3 * ND);
    unsigned int* regionA = wsu + 3 * ND + (size_t)EE * 4;
    float* gate   = (float*)regionA;
    int*   rowptr = (int*)regionA;
    int*   cursor = (int*)regionA + 150016;
    float* mvals  = (float*)(regionA + 400000);
    int*   winner = (int*)(regionA + 400000 + EE);
    int*   bsum   = winner + EE;
    double* gate_sum = (double*)(((uintptr_t)(bsum + NB_SCAN) + 7) & ~(uintptr_t)7);

    const int B = 256;
    const int grid_ND = (int)((ND + B - 1) / B);
    const int grid_S  = (SS + B - 1) / B;
    const int grid_E  = (EE + B - 1) / B;
    const int grid_N  = (NN + B - 1) / B;
    const int grid_spmm = (int)((NN * 64 + B - 1) / B);

    init_kernel<<<grid_ND, B, 0, stream>>>(user, item, z0, winner, gate_sum);
    gate_kernel<<<2048, B, 0, stream>>>(user, item, rows, cols, sidx, eps,
                                        W1, b1, W2, b2, gate, gate_sum);
    winner_kernel<<<grid_S, B, 0, stream>>>(sidx, winner);
    mvals_kernel<<<grid_E, B, 0, stream>>>(vals, winner, gate, mvals);
    deg_zero_kernel<<<grid_N, B, 0, stream>>>(cursor);
    hist_kernel<<<grid_E, B, 0, stream>>>(rows, cursor);
    scan1_kernel<<<NB_SCAN, 256, 0, stream>>>(cursor, rowptr, bsum);
    scan2_kernel<<<1, 1024, 0, stream>>>(bsum);
    scan3_kernel<<<grid_N, B, 0, stream>>>(rowptr, bsum, cursor);
    scatter_kernel<<<grid_E, B, 0, stream>>>(rows, cols, vals, mvals, rowptr, cursor, edata);

    spmm_packed_kernel<<<grid_spmm, B, 0, stream>>>(rowptr, edata, z0, z1);
    spmm_packed_kernel<<<grid_spmm, B, 0, stream>>>(rowptr, edata, z1, z2);
    spmm_packed_kernel<<<grid_spmm, B, 0, stream>>>(rowptr, edata, z2, z0);

    fold_kernel<<<grid_ND, B, 0, stream>>>(user, item, z1, z2, z0, outx, outy);
    final_kernel<<<1, 64, 0, stream>>>(gate_sum, out_scalar);
}